// Round 1
// baseline (285.213 us; speedup 1.0000x reference)
//
#include <hip/hip_runtime.h>
#include <hip/hip_bf16.h>
#include <stdint.h>

#define NB    32
#define CIN   128
#define HIN   56
#define HW    (HIN*HIN)     // 3136
#define OCH   256
#define OHW   54
#define SPB   (OHW*OHW)     // 2916 spatial outputs per batch
#define KSZ   (CIN*9)       // 1152 = GEMM K
#define BM    128
#define BK    64
#define NKS   (KSZ/BK)      // 18 K-steps
#define SPT   23            // ceil(2916/128) spatial tiles per batch

typedef __attribute__((ext_vector_type(8))) short bf16x8;
typedef __attribute__((ext_vector_type(4))) float f32x4;

// ---- pre-pass 1: x NCHW f32 -> NHWC bf16 (LDS tiled transpose) ----
__global__ void xpose_cast(const float* __restrict__ x, __hip_bfloat16* __restrict__ xt) {
    __shared__ float tile[32][33];
    const int hw0 = blockIdx.x * 32;
    const int c0  = blockIdx.y * 32;
    const int n   = blockIdx.z;
    const float* xp = x + ((size_t)n*CIN + c0)*HW + hw0;
    #pragma unroll
    for (int i = threadIdx.y; i < 32; i += 8)
        tile[i][threadIdx.x] = xp[(size_t)i*HW + threadIdx.x];
    __syncthreads();
    __hip_bfloat16* op = xt + ((size_t)n*HW + hw0)*CIN + c0;
    #pragma unroll
    for (int i = threadIdx.y; i < 32; i += 8)
        op[(size_t)i*CIN + threadIdx.x] = __float2bfloat16(tile[threadIdx.x][i]);
}

// ---- pre-pass 2: weight OIHW f32 -> [oc][(kh*3+kw)*128+ic] bf16 ----
__global__ void wcast(const float* __restrict__ w, __hip_bfloat16* __restrict__ wt) {
    int tid = blockIdx.x*256 + threadIdx.x;
    if (tid >= OCH*KSZ) return;
    int oc = tid / KSZ, r = tid % KSZ;
    int pos = r >> 7, ic = r & 127;           // r = pos*128 + ic
    wt[tid] = __float2bfloat16(w[((size_t)(oc*CIN + ic))*9 + pos]);
}

// ---- main: implicit-GEMM bf16 MFMA conv ----
// grid: (sptile 0..22, octile 0..1, n 0..31), block 256 (4 waves, 2x2 of 64x64)
__global__ __launch_bounds__(256, 2)
void conv_mfma(const __hip_bfloat16* __restrict__ xt,
               const __hip_bfloat16* __restrict__ wt,
               const float* __restrict__ bias,
               float* __restrict__ out) {
    // [row 0..127][8 granules of 16B], granule XOR-swizzled by (row&7)
    __shared__ uint4 Alds[BM*8];
    __shared__ uint4 Blds[BM*8];

    const int t = threadIdx.x;
    const int sptile = blockIdx.x;
    const int octile = blockIdx.y;
    const int n = blockIdx.z;

    // --- staging coords: each thread stages 64B of A and 64B of B per K-step
    const int srow  = t >> 1;      // 0..127
    const int shalf = t & 1;       // which 32-elem half of the 64-elem row
    const __hip_bfloat16* abase = wt + (size_t)(octile*BM + srow)*KSZ + shalf*32;
    int sp  = sptile*128 + srow;
    int spc = sp < SPB ? sp : SPB-1;             // clamp pad columns to a valid addr
    const int oh = spc / OHW, ow = spc % OHW;
    const __hip_bfloat16* bbase = xt + (((size_t)n*HIN + oh)*HIN + ow)*CIN + shalf*32;

    // --- mfma coords
    const int lane = t & 63;
    const int wid  = t >> 6;
    const int wm = wid >> 1, wn = wid & 1;       // 2x2 waves of 64x64
    const int lr = lane & 15, lq = lane >> 4;

    f32x4 acc[4][4];
    #pragma unroll
    for (int i = 0; i < 4; ++i)
        #pragma unroll
        for (int j = 0; j < 4; ++j)
            acc[i][j] = (f32x4){0.f, 0.f, 0.f, 0.f};

    for (int ks = 0; ks < NKS; ++ks) {
        // k = pos*128 + ic ; one BK=64 step stays inside one (kh,kw)
        const int pos = ks >> 1;
        const int ic0 = (ks & 1) * 64;
        const int kh = pos / 3, kw = pos - kh*3;

        // issue global loads before the barrier (latency hides under prior MFMA)
        uint4 av[4], bv[4];
        const uint4* ap = (const uint4*)(abase + ks*BK);
        const uint4* bp = (const uint4*)(bbase + ((size_t)kh*HIN + kw)*CIN + ic0);
        #pragma unroll
        for (int g = 0; g < 4; ++g) { av[g] = ap[g]; bv[g] = bp[g]; }

        __syncthreads();   // previous step's ds_reads done before overwrite
        #pragma unroll
        for (int g = 0; g < 4; ++g) {
            int gs = (shalf*4 + g) ^ (srow & 7);   // write-side swizzle
            Alds[srow*8 + gs] = av[g];
            Blds[srow*8 + gs] = bv[g];
        }
        __syncthreads();

        #pragma unroll
        for (int kk = 0; kk < 2; ++kk) {
            bf16x8 a[4], b[4];
            #pragma unroll
            for (int mi = 0; mi < 4; ++mi) {
                int r = wm*64 + mi*16 + lr;
                uint4 v = Alds[r*8 + ((kk*4 + lq) ^ (r & 7))];   // read-side swizzle
                a[mi] = *(bf16x8*)&v;
            }
            #pragma unroll
            for (int ni = 0; ni < 4; ++ni) {
                int r = wn*64 + ni*16 + lr;
                uint4 v = Blds[r*8 + ((kk*4 + lq) ^ (r & 7))];
                b[ni] = *(bf16x8*)&v;
            }
            #pragma unroll
            for (int mi = 0; mi < 4; ++mi)
                #pragma unroll
                for (int ni = 0; ni < 4; ++ni)
                    acc[mi][ni] = __builtin_amdgcn_mfma_f32_16x16x32_bf16(
                        a[mi], b[ni], acc[mi][ni], 0, 0, 0);
        }
    }

    // --- epilogue: C/D map col=lane&15, row=(lane>>4)*4+reg (m89-verified)
    #pragma unroll
    for (int mi = 0; mi < 4; ++mi) {
        const int ocl = octile*BM + wm*64 + mi*16 + lq*4;
        #pragma unroll
        for (int ni = 0; ni < 4; ++ni) {
            const int col = sptile*128 + wn*64 + ni*16 + lr;
            if (col < SPB) {
                #pragma unroll
                for (int r = 0; r < 4; ++r)
                    out[((size_t)n*OCH + ocl + r)*SPB + col] = acc[mi][ni][r] + bias[ocl + r];
            }
        }
    }
}

// ---- fallback (only if ws too small): direct fp32 conv ----
__global__ void conv_naive(const float* __restrict__ x, const float* __restrict__ w,
                           const float* __restrict__ bias, float* __restrict__ out) {
    size_t tid = (size_t)blockIdx.x*256 + threadIdx.x;
    const size_t total = (size_t)NB*OCH*SPB;
    if (tid >= total) return;
    int col = (int)(tid % SPB);
    int oc  = (int)((tid / SPB) % OCH);
    int n   = (int)(tid / ((size_t)SPB*OCH));
    int oh = col / OHW, ow = col % OHW;
    float s = bias[oc];
    for (int ic = 0; ic < CIN; ++ic)
        #pragma unroll
        for (int kh = 0; kh < 3; ++kh)
            #pragma unroll
            for (int kw = 0; kw < 3; ++kw)
                s += x[((size_t)(n*CIN+ic)*HIN + oh+kh)*HIN + ow+kw]
                   * w[((size_t)(oc*CIN+ic)*3 + kh)*3 + kw];
    out[tid] = s;
}

extern "C" void kernel_launch(void* const* d_in, const int* in_sizes, int n_in,
                              void* d_out, int out_size, void* d_ws, size_t ws_size,
                              hipStream_t stream) {
    const float* x    = (const float*)d_in[0];
    const float* w    = (const float*)d_in[1];
    const float* bias = (const float*)d_in[2];
    float* out = (float*)d_out;

    const size_t xt_bytes = (size_t)NB*HW*CIN*sizeof(__hip_bfloat16);   // 25,690,112
    const size_t wt_bytes = (size_t)OCH*KSZ*sizeof(__hip_bfloat16);     //    589,824

    if (ws_size >= xt_bytes + wt_bytes) {
        __hip_bfloat16* xt  = (__hip_bfloat16*)d_ws;
        __hip_bfloat16* wtp = (__hip_bfloat16*)((char*)d_ws + xt_bytes);
        hipLaunchKernelGGL(xpose_cast, dim3(HW/32, CIN/32, NB), dim3(32, 8), 0, stream, x, xt);
        hipLaunchKernelGGL(wcast, dim3((OCH*KSZ + 255)/256), dim3(256), 0, stream, w, wtp);
        hipLaunchKernelGGL(conv_mfma, dim3(SPT, OCH/BM, NB), dim3(256), 0, stream,
                           xt, wtp, bias, out);
    } else {
        size_t total = (size_t)NB*OCH*SPB;
        hipLaunchKernelGGL(conv_naive, dim3((unsigned)((total + 255)/256)), dim3(256), 0, stream,
                           x, w, bias, out);
    }
}

// Round 2
// 86.479 us; speedup vs baseline: 3.2981x; 3.2981x over previous
//
#include <hip/hip_runtime.h>
#include <hip/hip_bf16.h>
#include <stdint.h>

#define NB    32
#define CIN   128
#define HIN   56
#define HW    (HIN*HIN)     // 3136
#define OCH   256
#define OHW   54
#define SPB   (OHW*OHW)     // 2916 spatial outputs per batch
#define KSZ   (CIN*9)       // 1152 = GEMM K
#define BM    128
#define BK    64
#define NKS   (KSZ/BK)      // 18 K-steps
#define SPT   23            // ceil(2916/128)

typedef __attribute__((ext_vector_type(8))) short bf16x8;
typedef __attribute__((ext_vector_type(4))) float f32x4;

typedef __attribute__((address_space(1))) const uint32_t g_u32;
typedef __attribute__((address_space(3))) uint32_t l_u32;
static __device__ __forceinline__ void gl_lds16(const void* g, void* l) {
    __builtin_amdgcn_global_load_lds((g_u32*)g, (l_u32*)l, 16, 0, 0);
}

// ---- pre-pass 1: x NCHW f32 -> NHWC bf16 (LDS tiled transpose) ----
__global__ void xpose_cast(const float* __restrict__ x, __hip_bfloat16* __restrict__ xt) {
    __shared__ float tile[32][33];       // [c][hw]
    const int hw0 = blockIdx.x * 32;
    const int c0  = blockIdx.y * 32;
    const int n   = blockIdx.z;
    const int tx = threadIdx.x, ty = threadIdx.y;
    const float* xp = x + ((size_t)n*CIN + c0)*HW + hw0;
    #pragma unroll
    for (int i = ty; i < 32; i += 8)
        tile[i][tx] = xp[(size_t)i*HW + tx];
    __syncthreads();
    // 256 threads: t = hwl*8 + q ; each writes ushort4 (4 c's) -> 64B per 8 lanes
    const int t = ty*32 + tx;
    const int hwl = t >> 3, q = t & 7;
    ushort4 v;
    v.x = __bfloat16_as_ushort(__float2bfloat16(tile[q*4+0][hwl]));
    v.y = __bfloat16_as_ushort(__float2bfloat16(tile[q*4+1][hwl]));
    v.z = __bfloat16_as_ushort(__float2bfloat16(tile[q*4+2][hwl]));
    v.w = __bfloat16_as_ushort(__float2bfloat16(tile[q*4+3][hwl]));
    __hip_bfloat16* op = xt + ((size_t)n*HW + hw0 + hwl)*CIN + c0 + q*4;
    *(ushort4*)op = v;
}

// ---- pre-pass 2: weight OIHW f32 -> [oc][(kh*3+kw)*128+ic] bf16 ----
__global__ void wcast(const float* __restrict__ w, __hip_bfloat16* __restrict__ wt) {
    int tid = blockIdx.x*256 + threadIdx.x;
    if (tid >= OCH*KSZ) return;
    int oc = tid / KSZ, r = tid % KSZ;
    int pos = r >> 7, ic = r & 127;
    wt[tid] = __float2bfloat16(w[((size_t)(oc*CIN + ic))*9 + pos]);
}

// ---- main: implicit-GEMM bf16 MFMA conv ----
// grid (23, 2, 32), block 256 (4 waves = 2x2 of 64x64 sub-tiles)
__global__ __launch_bounds__(256, 2)
void conv_mfma(const __hip_bfloat16* __restrict__ xt,
               const __hip_bfloat16* __restrict__ wt,
               const float* __restrict__ bias,
               float* __restrict__ out) {
    // staging: A/B tiles, [128 rows][8 granules of 16B], content XOR-swizzled
    // (linear global_load_lds dest + inverse-swizzled SOURCE + swizzled read)
    __shared__ char smem[64*132*4 >= 32768 ? 64*132*4 : 32768];  // 33792 B
    uint4* Alds = (uint4*)smem;          // [0..1023]
    uint4* Blds = Alds + 1024;           // [1024..2047]
    float (*eps)[132] = (float (*)[132])smem;   // epilogue restage [64][132]

    const int t = threadIdx.x;
    const int sptile = blockIdx.x, octile = blockIdx.y, n = blockIdx.z;
    const int lane = t & 63, wid = t >> 6;
    const int wm = wid >> 1, wn = wid & 1;
    const int lr = lane & 15, lq = lane >> 4;

    // --- staging sources: issue i of wave wid covers linear granules
    //     p = wid*256 + i*64 + lane ; row = p>>3, gdest = p&7
    //     source granule = gdest ^ (row&7)  (so swizzled read recovers linear k)
    const __hip_bfloat16* asrc[4];
    const __hip_bfloat16* bsrc[4];
    #pragma unroll
    for (int i = 0; i < 4; ++i) {
        int p = wid*256 + i*64 + lane;
        int row = p >> 3;
        int g = (p & 7) ^ (row & 7);
        asrc[i] = wt + (size_t)(octile*BM + row)*KSZ + g*8;
        int sp = sptile*BM + row; if (sp >= SPB) sp = SPB - 1;   // clamp pad rows
        int oh = sp / OHW, ow = sp - oh*OHW;
        bsrc[i] = xt + ((size_t)(n*HIN + oh)*HIN + ow)*CIN + g*8;
    }

    auto issue = [&](int ks) {
        const int pos = ks >> 1;
        const int kh = pos / 3, kw = pos - kh*3;
        const int boff = (kh*HIN + kw)*CIN + (ks & 1)*64;
        const int aoff = ks*BK;
        #pragma unroll
        for (int i = 0; i < 4; ++i) {
            gl_lds16(asrc[i] + aoff, Alds + wid*256 + i*64);
            gl_lds16(bsrc[i] + boff, Blds + wid*256 + i*64);
        }
    };

    f32x4 acc[4][4];
    #pragma unroll
    for (int i = 0; i < 4; ++i)
        #pragma unroll
        for (int j = 0; j < 4; ++j)
            acc[i][j] = (f32x4){0.f, 0.f, 0.f, 0.f};

    issue(0);
    for (int ks = 0; ks < NKS; ++ks) {
        __syncthreads();                         // loads for ks landed (vmcnt drain)
        bf16x8 a[2][4], b[2][4];
        #pragma unroll
        for (int kk = 0; kk < 2; ++kk)
            #pragma unroll
            for (int mi = 0; mi < 4; ++mi) {
                int ra = wm*64 + mi*16 + lr;
                a[kk][mi] = *(bf16x8*)&Alds[ra*8 + ((kk*4 + lq) ^ (ra & 7))];
                int rb = wn*64 + mi*16 + lr;
                b[kk][mi] = *(bf16x8*)&Blds[rb*8 + ((kk*4 + lq) ^ (rb & 7))];
            }
        __syncthreads();                         // all reads done -> safe to overwrite
        if (ks + 1 < NKS) issue(ks + 1);         // fly under MFMA phase
        #pragma unroll
        for (int kk = 0; kk < 2; ++kk)
            #pragma unroll
            for (int mi = 0; mi < 4; ++mi)
                #pragma unroll
                for (int ni = 0; ni < 4; ++ni)
                    acc[mi][ni] = __builtin_amdgcn_mfma_f32_16x16x32_bf16(
                        a[kk][mi], b[kk][ni], acc[mi][ni], 0, 0, 0);
    }

    // --- epilogue: restage through LDS, fully-coalesced float4 stores ---
    // C/D map: row = lq*4 + r (oc), col = lr (sp)  [m89-verified orientation]
    for (int h = 0; h < 2; ++h) {
        if (wm == h) {
            #pragma unroll
            for (int mi = 0; mi < 4; ++mi) {
                int rl = mi*16 + lq*4;
                #pragma unroll
                for (int ni = 0; ni < 4; ++ni) {
                    int cl = wn*64 + ni*16 + lr;
                    #pragma unroll
                    for (int r = 0; r < 4; ++r)
                        eps[rl + r][cl] = acc[mi][ni][r];
                }
            }
        }
        __syncthreads();
        const int cl4 = (t & 31) * 4;
        const int colg = sptile*BM + cl4;
        const int rsub = t >> 5;                 // 0..7
        if (colg < SPB) {                        // SPB%4==0 -> whole-vec guard
            #pragma unroll
            for (int pass = 0; pass < 8; ++pass) {
                int rl = pass*8 + rsub;
                int rg = octile*BM + h*64 + rl;
                f32x4 v = *(f32x4*)&eps[rl][cl4];
                float bv = bias[rg];
                v = v + bv;
                *(f32x4*)&out[((size_t)n*OCH + rg)*SPB + colg] = v;
            }
        }
        __syncthreads();                         // before next half overwrites eps
    }
}

// ---- fallback (only if ws too small): direct fp32 conv ----
__global__ void conv_naive(const float* __restrict__ x, const float* __restrict__ w,
                           const float* __restrict__ bias, float* __restrict__ out) {
    size_t tid = (size_t)blockIdx.x*256 + threadIdx.x;
    const size_t total = (size_t)NB*OCH*SPB;
    if (tid >= total) return;
    int col = (int)(tid % SPB);
    int oc  = (int)((tid / SPB) % OCH);
    int n   = (int)(tid / ((size_t)SPB*OCH));
    int oh = col / OHW, ow = col % OHW;
    float s = bias[oc];
    for (int ic = 0; ic < CIN; ++ic)
        #pragma unroll
        for (int kh = 0; kh < 3; ++kh)
            #pragma unroll
            for (int kw = 0; kw < 3; ++kw)
                s += x[((size_t)(n*CIN+ic)*HIN + oh+kh)*HIN + ow+kw]
                   * w[((size_t)(oc*CIN+ic)*3 + kh)*3 + kw];
    out[tid] = s;
}

extern "C" void kernel_launch(void* const* d_in, const int* in_sizes, int n_in,
                              void* d_out, int out_size, void* d_ws, size_t ws_size,
                              hipStream_t stream) {
    const float* x    = (const float*)d_in[0];
    const float* w    = (const float*)d_in[1];
    const float* bias = (const float*)d_in[2];
    float* out = (float*)d_out;

    const size_t xt_bytes = (size_t)NB*HW*CIN*sizeof(__hip_bfloat16);   // 25,690,112
    const size_t wt_bytes = (size_t)OCH*KSZ*sizeof(__hip_bfloat16);     //    589,824

    if (ws_size >= xt_bytes + wt_bytes) {
        __hip_bfloat16* xt  = (__hip_bfloat16*)d_ws;
        __hip_bfloat16* wtp = (__hip_bfloat16*)((char*)d_ws + xt_bytes);
        hipLaunchKernelGGL(xpose_cast, dim3(HW/32, CIN/32, NB), dim3(32, 8), 0, stream, x, xt);
        hipLaunchKernelGGL(wcast, dim3((OCH*KSZ + 255)/256), dim3(256), 0, stream, w, wtp);
        hipLaunchKernelGGL(conv_mfma, dim3(SPT, OCH/BM, NB), dim3(256), 0, stream,
                           xt, wtp, bias, out);
    } else {
        size_t total = (size_t)NB*OCH*SPB;
        hipLaunchKernelGGL(conv_naive, dim3((unsigned)((total + 255)/256)), dim3(256), 0, stream,
                           x, w, bias, out);
    }
}